// Round 1
// baseline (746.992 us; speedup 1.0000x reference)
//
#include <hip/hip_runtime.h>
#include <math.h>

// SimpleGNN: out = softplus(A(relu(A(relu(A(x W1)+b1) W2)+b2) Wout)+bout)
// using spmm(x) @ W == spmm(x @ W) to make the last spmm D=1.

// ---------------- CSR build ----------------
__global__ void k_hist(const int* __restrict__ row, int* __restrict__ cnt, int E){
  int e = blockIdx.x*256 + threadIdx.x;
  if(e < E) atomicAdd(&cnt[row[e]], 1);
}

// per-tile exclusive scan (tile=1024); writes local-exclusive values + tile totals
__global__ void k_scan1(const int* __restrict__ cnt, int* __restrict__ scanned,
                        int* __restrict__ sums, int n){
  __shared__ int tmp[1024];
  int i = blockIdx.x*1024 + threadIdx.x;
  int v = (i<n)? cnt[i] : 0;
  tmp[threadIdx.x] = v;
  __syncthreads();
  for(int off=1; off<1024; off<<=1){
    int t = (threadIdx.x>=off)? tmp[threadIdx.x-off] : 0;
    __syncthreads();
    tmp[threadIdx.x] += t;
    __syncthreads();
  }
  if(i<n) scanned[i] = tmp[threadIdx.x] - v;      // local exclusive
  if(threadIdx.x==1023) sums[blockIdx.x] = tmp[1023];
}

__global__ void k_scan2(int* sums, int ntiles){
  if(threadIdx.x==0 && blockIdx.x==0){
    int acc=0;
    for(int i=0;i<ntiles;i++){ int v=sums[i]; sums[i]=acc; acc+=v; }
  }
}

__global__ void k_scan3(const int* __restrict__ scanned, const int* __restrict__ sums,
                        int* __restrict__ row_ptr, int* __restrict__ offs, int n, int E){
  int i = blockIdx.x*256 + threadIdx.x;
  if(i<n){ int ex = scanned[i] + sums[i>>10]; row_ptr[i]=ex; offs[i]=ex; }
  else if(i==n){ row_ptr[n]=E; }
}

__global__ void k_scatter(const int* __restrict__ row, const int* __restrict__ col,
                          const float* __restrict__ val, int* __restrict__ offs,
                          int* __restrict__ col_s, float* __restrict__ val_s, int E){
  int e = blockIdx.x*256 + threadIdx.x;
  if(e<E){
    int p = atomicAdd(&offs[row[e]],1);
    col_s[p]=col[e]; val_s[p]=val[e];
  }
}

// ---------------- dense GEMM: Y[n,128] = X[n,128] @ W[128,128] ----------------
// 128x128 block tile, BK=32, 256 threads, 8x8 per-thread register tile.
__global__ __launch_bounds__(256) void k_gemm(const float* __restrict__ X,
                                              const float* __restrict__ W,
                                              float* __restrict__ Y, int n){
  __shared__ float xs_t[32][128];   // [k][row] transposed x tile
  __shared__ float ws[32][128];     // [k][col]
  const int t   = threadIdx.x;
  const int row0 = blockIdx.x * 128;
  const int cg  = t & 15;           // col group: cols cg*8 .. cg*8+7
  const int rg  = t >> 4;           // row group: rows rg*8 .. rg*8+7

  float acc[8][8];
  #pragma unroll
  for(int i=0;i<8;i++)
    #pragma unroll
    for(int j=0;j<8;j++) acc[i][j]=0.f;

  for(int kt=0; kt<128; kt+=32){
    // stage x transposed: thread -> row r = t>>1, half q = t&1 (16 floats)
    {
      int r = t>>1, q = t&1;
      int gr = row0 + r;
      float4 a = make_float4(0,0,0,0), b = a, c = a, d = a;
      if(gr < n){
        const float4* src = (const float4*)(X + (size_t)gr*128 + kt + q*16);
        a = src[0]; b = src[1]; c = src[2]; d = src[3];
      }
      int kb = q*16;
      xs_t[kb+ 0][r]=a.x; xs_t[kb+ 1][r]=a.y; xs_t[kb+ 2][r]=a.z; xs_t[kb+ 3][r]=a.w;
      xs_t[kb+ 4][r]=b.x; xs_t[kb+ 5][r]=b.y; xs_t[kb+ 6][r]=b.z; xs_t[kb+ 7][r]=b.w;
      xs_t[kb+ 8][r]=c.x; xs_t[kb+ 9][r]=c.y; xs_t[kb+10][r]=c.z; xs_t[kb+11][r]=c.w;
      xs_t[kb+12][r]=d.x; xs_t[kb+13][r]=d.y; xs_t[kb+14][r]=d.z; xs_t[kb+15][r]=d.w;
    }
    // stage W: linear float4 mapping (coalesced, conflict-free)
    #pragma unroll
    for(int rep=0; rep<4; rep++){
      int f  = t + rep*256;        // float4 index in [0,1024)
      int kr = f >> 5;             // 32 float4 per k-row
      int cq = f & 31;
      float4 w = *(const float4*)(W + (size_t)(kt+kr)*128 + cq*4);
      *(float4*)&ws[kr][cq*4] = w;
    }
    __syncthreads();

    #pragma unroll
    for(int kk=0; kk<32; kk++){
      float4 wv0 = *(const float4*)&ws[kk][cg*8];
      float4 wv1 = *(const float4*)&ws[kk][cg*8+4];
      #pragma unroll
      for(int i=0;i<8;i++){
        float xv = xs_t[kk][rg*8+i];
        acc[i][0] = fmaf(xv, wv0.x, acc[i][0]);
        acc[i][1] = fmaf(xv, wv0.y, acc[i][1]);
        acc[i][2] = fmaf(xv, wv0.z, acc[i][2]);
        acc[i][3] = fmaf(xv, wv0.w, acc[i][3]);
        acc[i][4] = fmaf(xv, wv1.x, acc[i][4]);
        acc[i][5] = fmaf(xv, wv1.y, acc[i][5]);
        acc[i][6] = fmaf(xv, wv1.z, acc[i][6]);
        acc[i][7] = fmaf(xv, wv1.w, acc[i][7]);
      }
    }
    __syncthreads();
  }

  #pragma unroll
  for(int i=0;i<8;i++){
    int gr = row0 + rg*8 + i;
    if(gr < n){
      float* dst = Y + (size_t)gr*128 + cg*8;
      *(float4*)dst     = make_float4(acc[i][0],acc[i][1],acc[i][2],acc[i][3]);
      *(float4*)(dst+4) = make_float4(acc[i][4],acc[i][5],acc[i][6],acc[i][7]);
    }
  }
}

// ---------------- SpMM (D=128) + bias + relu: h[r] = relu(sum val*y[col] + b) ----------------
// one wave per row, float2 per lane
__global__ __launch_bounds__(256) void k_spmm_relu(const int* __restrict__ row_ptr,
                                                   const int* __restrict__ col_s,
                                                   const float* __restrict__ val_s,
                                                   const float* __restrict__ y,
                                                   const float* __restrict__ bias,
                                                   float* __restrict__ h, int n){
  int wid  = (int)((blockIdx.x*(size_t)blockDim.x + threadIdx.x) >> 6);
  int lane = threadIdx.x & 63;
  if(wid >= n) return;
  int s = row_ptr[wid], e = row_ptr[wid+1];
  float2 acc = make_float2(0.f, 0.f);
  for(int i=s; i<e; i++){
    int   c = col_s[i];
    float v = val_s[i];
    float2 xv = ((const float2*)(y + (size_t)c*128))[lane];
    acc.x = fmaf(v, xv.x, acc.x);
    acc.y = fmaf(v, xv.y, acc.y);
  }
  float2 b = ((const float2*)bias)[lane];
  acc.x = fmaxf(acc.x + b.x, 0.f);
  acc.y = fmaxf(acc.y + b.y, 0.f);
  ((float2*)(h + (size_t)wid*128))[lane] = acc;
}

// ---------------- head: z[r] = h[r] . Wout ----------------
__global__ __launch_bounds__(256) void k_head_dot(const float* __restrict__ h,
                                                  const float* __restrict__ Wout,
                                                  float* __restrict__ z, int n){
  int wid  = (int)((blockIdx.x*(size_t)blockDim.x + threadIdx.x) >> 6);
  int lane = threadIdx.x & 63;
  if(wid >= n) return;
  float2 hv = ((const float2*)(h + (size_t)wid*128))[lane];
  float2 wv = ((const float2*)Wout)[lane];
  float p = hv.x*wv.x + hv.y*wv.y;
  #pragma unroll
  for(int off=32; off; off>>=1) p += __shfl_down(p, off);
  if(lane==0) z[wid] = p;
}

// ---------------- final: out[r] = softplus(sum val*z[col] + bout) ----------------
__global__ void k_spmm1_softplus(const int* __restrict__ row_ptr,
                                 const int* __restrict__ col_s,
                                 const float* __restrict__ val_s,
                                 const float* __restrict__ z,
                                 const float* __restrict__ bout,
                                 float* __restrict__ out, int n){
  int r = blockIdx.x*256 + threadIdx.x;
  if(r >= n) return;
  int s = row_ptr[r], e = row_ptr[r+1];
  float acc = 0.f;
  for(int i=s; i<e; i++) acc = fmaf(val_s[i], z[col_s[i]], acc);
  float x = acc + bout[0];
  out[r] = fmaxf(x, 0.f) + log1pf(expf(-fabsf(x)));   // stable softplus
}

extern "C" void kernel_launch(void* const* d_in, const int* in_sizes, int n_in,
                              void* d_out, int out_size, void* d_ws, size_t ws_size,
                              hipStream_t stream){
  const float* x    = (const float*)d_in[0];
  const int*   erow = (const int*)d_in[1];
  const int*   ecol = (const int*)d_in[2];
  const float* eval = (const float*)d_in[3];
  const float* W1   = (const float*)d_in[4];
  const float* b1   = (const float*)d_in[5];
  const float* W2   = (const float*)d_in[6];
  const float* b2   = (const float*)d_in[7];
  const float* Wout = (const float*)d_in[8];
  const float* bout = (const float*)d_in[9];
  float* out = (float*)d_out;

  const int N = in_sizes[0] / 128;   // 100000
  const int E = in_sizes[1];         // 1600000

  char* p = (char*)d_ws;
  auto alloc = [&](size_t bytes)->char*{
    char* r = p; p += (bytes + 255) & ~(size_t)255; return r;
  };
  int*   cnt     = (int*)  alloc((size_t)N*4);
  int*   row_ptr = (int*)  alloc((size_t)(N+1)*4);
  int*   offs    = (int*)  alloc((size_t)N*4);
  int*   scanned = (int*)  alloc((size_t)N*4);
  int*   sums    = (int*)  alloc(4096);
  int*   col_s   = (int*)  alloc((size_t)E*4);
  float* val_s   = (float*)alloc((size_t)E*4);
  float* ybuf    = (float*)alloc((size_t)N*128*4);
  float* hbuf    = (float*)alloc((size_t)N*128*4);
  float* z       = (float*)alloc((size_t)N*4);

  // CSR build
  hipMemsetAsync(cnt, 0, (size_t)N*4, stream);
  k_hist<<<(E+255)/256, 256, 0, stream>>>(erow, cnt, E);
  int ntiles = (N+1023)/1024;
  k_scan1<<<ntiles, 1024, 0, stream>>>(cnt, scanned, sums, N);
  k_scan2<<<1, 64, 0, stream>>>(sums, ntiles);
  k_scan3<<<(N+1+255)/256, 256, 0, stream>>>(scanned, sums, row_ptr, offs, N, E);
  k_scatter<<<(E+255)/256, 256, 0, stream>>>(erow, ecol, eval, offs, col_s, val_s, E);

  // layer 1: y = x@W1 ; h = relu(A y + b1)
  k_gemm<<<(N+127)/128, 256, 0, stream>>>(x, W1, ybuf, N);
  k_spmm_relu<<<(N+3)/4, 256, 0, stream>>>(row_ptr, col_s, val_s, ybuf, b1, hbuf, N);
  // layer 2: y = h@W2 ; h = relu(A y + b2)
  k_gemm<<<(N+127)/128, 256, 0, stream>>>(hbuf, W2, ybuf, N);
  k_spmm_relu<<<(N+3)/4, 256, 0, stream>>>(row_ptr, col_s, val_s, ybuf, b2, hbuf, N);
  // head: z = h@Wout ; out = softplus(A z + bout)
  k_head_dot<<<(N+3)/4, 256, 0, stream>>>(hbuf, Wout, z, N);
  k_spmm1_softplus<<<(N+255)/256, 256, 0, stream>>>(row_ptr, col_s, val_s, z, bout, out, N);
}

// Round 4
// 630.556 us; speedup vs baseline: 1.1847x; 1.1847x over previous
//
#include <hip/hip_runtime.h>
#include <math.h>

// SimpleGNN: out = softplus(A(relu(A(relu(A(x W1)+b1) W2)+b2) Wout)+bout)
// using spmm(x) @ W == spmm(x @ W) to make the last spmm D=1.

// ---------------- CSR build ----------------
__global__ void k_hist(const int* __restrict__ row, int* __restrict__ cnt, int E){
  int e = blockIdx.x*256 + threadIdx.x;
  if(e < E) atomicAdd(&cnt[row[e]], 1);
}

// per-tile exclusive scan (tile=1024); writes local-exclusive values + tile totals
__global__ void k_scan1(const int* __restrict__ cnt, int* __restrict__ scanned,
                        int* __restrict__ sums, int n){
  __shared__ int tmp[1024];
  int i = blockIdx.x*1024 + threadIdx.x;
  int v = (i<n)? cnt[i] : 0;
  tmp[threadIdx.x] = v;
  __syncthreads();
  for(int off=1; off<1024; off<<=1){
    int t = (threadIdx.x>=off)? tmp[threadIdx.x-off] : 0;
    __syncthreads();
    tmp[threadIdx.x] += t;
    __syncthreads();
  }
  if(i<n) scanned[i] = tmp[threadIdx.x] - v;      // local exclusive
  if(threadIdx.x==1023) sums[blockIdx.x] = tmp[1023];
}

__global__ void k_scan2(int* sums, int ntiles){
  if(threadIdx.x==0 && blockIdx.x==0){
    int acc=0;
    for(int i=0;i<ntiles;i++){ int v=sums[i]; sums[i]=acc; acc+=v; }
  }
}

__global__ void k_scan3(const int* __restrict__ scanned, const int* __restrict__ sums,
                        int* __restrict__ row_ptr, int* __restrict__ offs, int n, int E){
  int i = blockIdx.x*256 + threadIdx.x;
  if(i<n){ int ex = scanned[i] + sums[i>>10]; row_ptr[i]=ex; offs[i]=ex; }
  else if(i==n){ row_ptr[n]=E; }
}

__global__ void k_scatter(const int* __restrict__ row, const int* __restrict__ col,
                          const float* __restrict__ val, int* __restrict__ offs,
                          int* __restrict__ col_s, float* __restrict__ val_s, int E){
  int e = blockIdx.x*256 + threadIdx.x;
  if(e<E){
    int p = atomicAdd(&offs[row[e]],1);
    col_s[p]=col[e]; val_s[p]=val[e];
  }
}

// ---------------- dense GEMM: Y[n,128] = X[n,128] @ W[128,128] ----------------
// 128x128 block tile, BK=32, 256 threads, 8x8 per-thread register tile.
__global__ __launch_bounds__(256) void k_gemm(const float* __restrict__ X,
                                              const float* __restrict__ W,
                                              float* __restrict__ Y, int n){
  __shared__ float xs_t[32][128];   // [k][row] transposed x tile
  __shared__ float ws[32][128];     // [k][col]
  const int t   = threadIdx.x;
  const int row0 = blockIdx.x * 128;
  const int cg  = t & 15;           // col group: cols cg*8 .. cg*8+7
  const int rg  = t >> 4;           // row group: rows rg*8 .. rg*8+7

  float acc[8][8];
  #pragma unroll
  for(int i=0;i<8;i++)
    #pragma unroll
    for(int j=0;j<8;j++) acc[i][j]=0.f;

  for(int kt=0; kt<128; kt+=32){
    // stage x transposed: thread -> row r = t>>1, half q = t&1 (16 floats)
    {
      int r = t>>1, q = t&1;
      int gr = row0 + r;
      float4 a = make_float4(0,0,0,0), b = a, c = a, d = a;
      if(gr < n){
        const float4* src = (const float4*)(X + (size_t)gr*128 + kt + q*16);
        a = src[0]; b = src[1]; c = src[2]; d = src[3];
      }
      int kb = q*16;
      xs_t[kb+ 0][r]=a.x; xs_t[kb+ 1][r]=a.y; xs_t[kb+ 2][r]=a.z; xs_t[kb+ 3][r]=a.w;
      xs_t[kb+ 4][r]=b.x; xs_t[kb+ 5][r]=b.y; xs_t[kb+ 6][r]=b.z; xs_t[kb+ 7][r]=b.w;
      xs_t[kb+ 8][r]=c.x; xs_t[kb+ 9][r]=c.y; xs_t[kb+10][r]=c.z; xs_t[kb+11][r]=c.w;
      xs_t[kb+12][r]=d.x; xs_t[kb+13][r]=d.y; xs_t[kb+14][r]=d.z; xs_t[kb+15][r]=d.w;
    }
    // stage W: linear float4 mapping (coalesced, conflict-free)
    #pragma unroll
    for(int rep=0; rep<4; rep++){
      int f  = t + rep*256;        // float4 index in [0,1024)
      int kr = f >> 5;             // 32 float4 per k-row
      int cq = f & 31;
      float4 w = *(const float4*)(W + (size_t)(kt+kr)*128 + cq*4);
      *(float4*)&ws[kr][cq*4] = w;
    }
    __syncthreads();

    #pragma unroll
    for(int kk=0; kk<32; kk++){
      float4 wv0 = *(const float4*)&ws[kk][cg*8];
      float4 wv1 = *(const float4*)&ws[kk][cg*8+4];
      #pragma unroll
      for(int i=0;i<8;i++){
        float xv = xs_t[kk][rg*8+i];
        acc[i][0] = fmaf(xv, wv0.x, acc[i][0]);
        acc[i][1] = fmaf(xv, wv0.y, acc[i][1]);
        acc[i][2] = fmaf(xv, wv0.z, acc[i][2]);
        acc[i][3] = fmaf(xv, wv0.w, acc[i][3]);
        acc[i][4] = fmaf(xv, wv1.x, acc[i][4]);
        acc[i][5] = fmaf(xv, wv1.y, acc[i][5]);
        acc[i][6] = fmaf(xv, wv1.z, acc[i][6]);
        acc[i][7] = fmaf(xv, wv1.w, acc[i][7]);
      }
    }
    __syncthreads();
  }

  #pragma unroll
  for(int i=0;i<8;i++){
    int gr = row0 + rg*8 + i;
    if(gr < n){
      float* dst = Y + (size_t)gr*128 + cg*8;
      *(float4*)dst     = make_float4(acc[i][0],acc[i][1],acc[i][2],acc[i][3]);
      *(float4*)(dst+4) = make_float4(acc[i][4],acc[i][5],acc[i][6],acc[i][7]);
    }
  }
}

// ---------------- SpMM (D=128) + bias + relu: h[r] = relu(sum val*y[col] + b) ----------------
// one wave per row, float2 per lane, 4-wide edge unroll for ILP (4 gathers in flight)
__global__ __launch_bounds__(256) void k_spmm_relu(const int* __restrict__ row_ptr,
                                                   const int* __restrict__ col_s,
                                                   const float* __restrict__ val_s,
                                                   const float* __restrict__ y,
                                                   const float* __restrict__ bias,
                                                   float* __restrict__ h, int n){
  int wid  = (int)((blockIdx.x*(size_t)blockDim.x + threadIdx.x) >> 6);
  int lane = threadIdx.x & 63;
  if(wid >= n) return;
  int s = row_ptr[wid], e = row_ptr[wid+1];
  float2 a0 = make_float2(0.f,0.f), a1 = a0, a2 = a0, a3 = a0;
  int i = s;
  for(; i+4 <= e; i += 4){
    int   c0 = col_s[i],   c1 = col_s[i+1], c2 = col_s[i+2], c3 = col_s[i+3];
    float v0 = val_s[i],   v1 = val_s[i+1], v2 = val_s[i+2], v3 = val_s[i+3];
    float2 x0 = ((const float2*)(y + (size_t)c0*128))[lane];
    float2 x1 = ((const float2*)(y + (size_t)c1*128))[lane];
    float2 x2 = ((const float2*)(y + (size_t)c2*128))[lane];
    float2 x3 = ((const float2*)(y + (size_t)c3*128))[lane];
    a0.x = fmaf(v0, x0.x, a0.x); a0.y = fmaf(v0, x0.y, a0.y);
    a1.x = fmaf(v1, x1.x, a1.x); a1.y = fmaf(v1, x1.y, a1.y);
    a2.x = fmaf(v2, x2.x, a2.x); a2.y = fmaf(v2, x2.y, a2.y);
    a3.x = fmaf(v3, x3.x, a3.x); a3.y = fmaf(v3, x3.y, a3.y);
  }
  for(; i < e; i++){
    int   c = col_s[i];
    float v = val_s[i];
    float2 xv = ((const float2*)(y + (size_t)c*128))[lane];
    a0.x = fmaf(v, xv.x, a0.x); a0.y = fmaf(v, xv.y, a0.y);
  }
  float2 acc = make_float2((a0.x+a1.x)+(a2.x+a3.x), (a0.y+a1.y)+(a2.y+a3.y));
  float2 b = ((const float2*)bias)[lane];
  acc.x = fmaxf(acc.x + b.x, 0.f);
  acc.y = fmaxf(acc.y + b.y, 0.f);
  ((float2*)(h + (size_t)wid*128))[lane] = acc;
}

// ---------------- SpMM + bias + relu + head dot, fused: z[r] = relu(A y + b) . Wout ----------------
__global__ __launch_bounds__(256) void k_spmm_head(const int* __restrict__ row_ptr,
                                                   const int* __restrict__ col_s,
                                                   const float* __restrict__ val_s,
                                                   const float* __restrict__ y,
                                                   const float* __restrict__ bias,
                                                   const float* __restrict__ Wout,
                                                   float* __restrict__ z, int n){
  int wid  = (int)((blockIdx.x*(size_t)blockDim.x + threadIdx.x) >> 6);
  int lane = threadIdx.x & 63;
  if(wid >= n) return;
  int s = row_ptr[wid], e = row_ptr[wid+1];
  float2 a0 = make_float2(0.f,0.f), a1 = a0, a2 = a0, a3 = a0;
  int i = s;
  for(; i+4 <= e; i += 4){
    int   c0 = col_s[i],   c1 = col_s[i+1], c2 = col_s[i+2], c3 = col_s[i+3];
    float v0 = val_s[i],   v1 = val_s[i+1], v2 = val_s[i+2], v3 = val_s[i+3];
    float2 x0 = ((const float2*)(y + (size_t)c0*128))[lane];
    float2 x1 = ((const float2*)(y + (size_t)c1*128))[lane];
    float2 x2 = ((const float2*)(y + (size_t)c2*128))[lane];
    float2 x3 = ((const float2*)(y + (size_t)c3*128))[lane];
    a0.x = fmaf(v0, x0.x, a0.x); a0.y = fmaf(v0, x0.y, a0.y);
    a1.x = fmaf(v1, x1.x, a1.x); a1.y = fmaf(v1, x1.y, a1.y);
    a2.x = fmaf(v2, x2.x, a2.x); a2.y = fmaf(v2, x2.y, a2.y);
    a3.x = fmaf(v3, x3.x, a3.x); a3.y = fmaf(v3, x3.y, a3.y);
  }
  for(; i < e; i++){
    int   c = col_s[i];
    float v = val_s[i];
    float2 xv = ((const float2*)(y + (size_t)c*128))[lane];
    a0.x = fmaf(v, xv.x, a0.x); a0.y = fmaf(v, xv.y, a0.y);
  }
  float2 acc = make_float2((a0.x+a1.x)+(a2.x+a3.x), (a0.y+a1.y)+(a2.y+a3.y));
  float2 b  = ((const float2*)bias)[lane];
  float2 wv = ((const float2*)Wout)[lane];
  float hx = fmaxf(acc.x + b.x, 0.f);
  float hy = fmaxf(acc.y + b.y, 0.f);
  float p = hx*wv.x + hy*wv.y;
  #pragma unroll
  for(int off=32; off; off>>=1) p += __shfl_down(p, off);
  if(lane==0) z[wid] = p;
}

// ---------------- final: out[r] = softplus(sum val*z[col] + bout) ----------------
__global__ void k_spmm1_softplus(const int* __restrict__ row_ptr,
                                 const int* __restrict__ col_s,
                                 const float* __restrict__ val_s,
                                 const float* __restrict__ z,
                                 const float* __restrict__ bout,
                                 float* __restrict__ out, int n){
  int r = blockIdx.x*256 + threadIdx.x;
  if(r >= n) return;
  int s = row_ptr[r], e = row_ptr[r+1];
  float a0=0.f, a1=0.f, a2=0.f, a3=0.f;
  int i = s;
  for(; i+4 <= e; i += 4){
    float z0 = z[col_s[i]],   z1 = z[col_s[i+1]];
    float z2 = z[col_s[i+2]], z3 = z[col_s[i+3]];
    a0 = fmaf(val_s[i],   z0, a0);
    a1 = fmaf(val_s[i+1], z1, a1);
    a2 = fmaf(val_s[i+2], z2, a2);
    a3 = fmaf(val_s[i+3], z3, a3);
  }
  for(; i < e; i++) a0 = fmaf(val_s[i], z[col_s[i]], a0);
  float x = (a0+a1)+(a2+a3) + bout[0];
  out[r] = fmaxf(x, 0.f) + log1pf(expf(-fabsf(x)));   // stable softplus
}

extern "C" void kernel_launch(void* const* d_in, const int* in_sizes, int n_in,
                              void* d_out, int out_size, void* d_ws, size_t ws_size,
                              hipStream_t stream){
  const float* x    = (const float*)d_in[0];
  const int*   erow = (const int*)d_in[1];
  const int*   ecol = (const int*)d_in[2];
  const float* eval = (const float*)d_in[3];
  const float* W1   = (const float*)d_in[4];
  const float* b1   = (const float*)d_in[5];
  const float* W2   = (const float*)d_in[6];
  const float* b2   = (const float*)d_in[7];
  const float* Wout = (const float*)d_in[8];
  const float* bout = (const float*)d_in[9];
  float* out = (float*)d_out;

  const int N = in_sizes[0] / 128;   // 100000
  const int E = in_sizes[1];         // 1600000

  char* p = (char*)d_ws;
  auto alloc = [&](size_t bytes)->char*{
    char* r = p; p += (bytes + 255) & ~(size_t)255; return r;
  };
  int*   cnt     = (int*)  alloc((size_t)N*4);
  int*   row_ptr = (int*)  alloc((size_t)(N+1)*4);
  int*   offs    = (int*)  alloc((size_t)N*4);
  int*   scanned = (int*)  alloc((size_t)N*4);
  int*   sums    = (int*)  alloc(4096);
  int*   col_s   = (int*)  alloc((size_t)E*4);
  float* val_s   = (float*)alloc((size_t)E*4);
  float* ybuf    = (float*)alloc((size_t)N*128*4);
  float* hbuf    = (float*)alloc((size_t)N*128*4);
  float* z       = (float*)alloc((size_t)N*4);

  // CSR build
  hipMemsetAsync(cnt, 0, (size_t)N*4, stream);
  k_hist<<<(E+255)/256, 256, 0, stream>>>(erow, cnt, E);
  int ntiles = (N+1023)/1024;
  k_scan1<<<ntiles, 1024, 0, stream>>>(cnt, scanned, sums, N);
  k_scan2<<<1, 64, 0, stream>>>(sums, ntiles);
  k_scan3<<<(N+1+255)/256, 256, 0, stream>>>(scanned, sums, row_ptr, offs, N, E);
  k_scatter<<<(E+255)/256, 256, 0, stream>>>(erow, ecol, eval, offs, col_s, val_s, E);

  // layer 1: y = x@W1 ; h = relu(A y + b1)
  k_gemm<<<(N+127)/128, 256, 0, stream>>>(x, W1, ybuf, N);
  k_spmm_relu<<<(N+3)/4, 256, 0, stream>>>(row_ptr, col_s, val_s, ybuf, b1, hbuf, N);
  // layer 2: y = h@W2 ; z = relu(A y + b2) . Wout   (head fused into spmm)
  k_gemm<<<(N+127)/128, 256, 0, stream>>>(hbuf, W2, ybuf, N);
  k_spmm_head<<<(N+3)/4, 256, 0, stream>>>(row_ptr, col_s, val_s, ybuf, b2, Wout, z, N);
  // out = softplus(A z + bout)
  k_spmm1_softplus<<<(N+255)/256, 256, 0, stream>>>(row_ptr, col_s, val_s, z, bout, out, N);
}